// Round 1
// baseline (211.122 us; speedup 1.0000x reference)
//
#include <hip/hip_runtime.h>

// Problem constants (from reference): B=64, M=16, T=2048, L=64, K=32, N=1985
#define B_ 64
#define M_ 16
#define T_ 2048
#define L_ 64
#define K_ 32
#define N_ (T_ - L_ + 1)   // 1985
#define TN 128             // n-positions per block tile
#define NTHREADS 128       // 16 n-groups (8n each) x 8 k-groups (4k each)

// out[b,k] = min_n sum_m pen[k,m,n] * ( sqwin[b,m,n] - 2*corr[b,m,n,k] + ss[k] )
// pen = elu(-pmap)+2 >= 1, raw >= 0  ->  wd >= 0, so uint atomicMin on float bits is valid.

__global__ void init_out_kernel(unsigned* __restrict__ out) {
    int i = blockIdx.x * 256 + threadIdx.x;
    if (i < B_ * K_) out[i] = 0x7F800000u;  // +inf
}

__global__ __launch_bounds__(NTHREADS, 2)
void shapelet_kernel(const float* __restrict__ x,
                     const float* __restrict__ shp,
                     const float* __restrict__ pmap,
                     unsigned* __restrict__ out) {
    // LDS: 12288 + 8192 + 8192 + 128 = 28800 B -> 4 blocks/CU within 160 KiB
    __shared__ __align__(16) float xs[M_][TN + L_];   // x slice, zero-padded past T
    __shared__ __align__(16) float sh_t[L_][K_];      // shapelets transposed [l][k]
    __shared__ __align__(16) float sqw[M_][TN];       // sliding window sum of x^2
    __shared__ __align__(16) float ss_l[K_];          // sum of s^2 per shapelet

    const int tid = threadIdx.x;
    const int b  = blockIdx.y;
    const int n0 = blockIdx.x * TN;

    // ---- stage x[b, :, n0 .. n0+191] (zero-fill past T) ----
    const float* xb = x + (size_t)b * (M_ * T_);
    for (int i = tid; i < M_ * (TN + L_); i += NTHREADS) {
        int m = i / (TN + L_);
        int j = i - m * (TN + L_);
        int t = n0 + j;
        xs[m][j] = (t < T_) ? xb[m * T_ + t] : 0.0f;
    }
    // ---- stage shapelets transposed (conflict-free LDS writes) ----
    for (int i = tid; i < K_ * L_; i += NTHREADS) {
        int k = i & (K_ - 1);
        int l = i >> 5;
        sh_t[l][k] = shp[k * L_ + l];
    }
    // ---- ss[k] = sum_l s[k,l]^2 ----
    if (tid < K_) {
        float s = 0.f;
        for (int l = 0; l < L_; ++l) { float v = shp[tid * L_ + l]; s = fmaf(v, v, s); }
        ss_l[tid] = s;
    }
    __syncthreads();

    // ---- sqw[m][j] = sum_{l<64} xs[m][j+l]^2 via sliding window (16 entries/thread) ----
    {
        int m  = tid >> 3;
        int j0 = (tid & 7) * 16;
        float s = 0.f;
        for (int l = 0; l < L_; ++l) { float v = xs[m][j0 + l]; s = fmaf(v, v, s); }
        sqw[m][j0] = s;
        for (int d = 1; d < 16; ++d) {
            float a = xs[m][j0 + d + L_ - 1];
            float r = xs[m][j0 + d - 1];
            s += a * a - r * r;
            sqw[m][j0 + d] = s;
        }
    }
    __syncthreads();

    // ---- per-thread micro-tile: 8 consecutive n x 4 k ----
    const int nig = tid & 15;        // n-group within tile
    const int kig = tid >> 4;        // k-group
    const int jb  = nig * 8;         // n offset in tile (32B aligned)
    const int kb  = kig * 4;

    float ssk[4];
#pragma unroll
    for (int kk = 0; kk < 4; ++kk) ssk[kk] = ss_l[kb + kk];

    float acc[8][4];                 // sum_m pen*(sqw + ss - 2*corr)
#pragma unroll
    for (int i = 0; i < 8; ++i)
#pragma unroll
        for (int kk = 0; kk < 4; ++kk) acc[i][kk] = 0.f;

    for (int m2 = 0; m2 < M_; m2 += 2) {
        float c0[8][4], c1[8][4];
#pragma unroll
        for (int i = 0; i < 8; ++i)
#pragma unroll
            for (int kk = 0; kk < 4; ++kk) { c0[i][kk] = 0.f; c1[i][kk] = 0.f; }

        // rotating 16-float register windows over xs[m][jb + ...]
        float wv0[16], wv1[16];
        *(float4*)&wv0[0] = *(const float4*)&xs[m2    ][jb];
        *(float4*)&wv0[4] = *(const float4*)&xs[m2    ][jb + 4];
        *(float4*)&wv1[0] = *(const float4*)&xs[m2 + 1][jb];
        *(float4*)&wv1[4] = *(const float4*)&xs[m2 + 1][jb + 4];

        for (int cc = 0; cc < 4; ++cc) {           // 4 x 4 chunks = 64 l-steps
#pragma unroll
            for (int p = 0; p < 4; ++p) {
                const int ch  = cc * 4 + p;
                const int dst = ((p + 2) * 4) & 15;  // slot of chunk ch+2
                *(float4*)&wv0[dst] = *(const float4*)&xs[m2    ][jb + (ch + 2) * 4];
                *(float4*)&wv1[dst] = *(const float4*)&xs[m2 + 1][jb + (ch + 2) * 4];
#pragma unroll
                for (int dl = 0; dl < 4; ++dl) {
                    const int l = ch * 4 + dl;
                    const float4 s4 = *(const float4*)&sh_t[l][kb];
#pragma unroll
                    for (int i = 0; i < 8; ++i) {
                        const int o = (p * 4 + dl + i) & 15;
                        const float xv0 = wv0[o];
                        const float xv1 = wv1[o];
                        c0[i][0] = fmaf(xv0, s4.x, c0[i][0]);
                        c0[i][1] = fmaf(xv0, s4.y, c0[i][1]);
                        c0[i][2] = fmaf(xv0, s4.z, c0[i][2]);
                        c0[i][3] = fmaf(xv0, s4.w, c0[i][3]);
                        c1[i][0] = fmaf(xv1, s4.x, c1[i][0]);
                        c1[i][1] = fmaf(xv1, s4.y, c1[i][1]);
                        c1[i][2] = fmaf(xv1, s4.z, c1[i][2]);
                        c1[i][3] = fmaf(xv1, s4.w, c1[i][3]);
                    }
                }
            }
        }

        // ---- apply penalty for the two m's (pen computed on the fly) ----
#pragma unroll
        for (int mm = 0; mm < 2; ++mm) {
            const int m = m2 + mm;
            float (&c)[8][4] = (mm == 0) ? c0 : c1;
            float sq[8];
            *(float4*)&sq[0] = *(const float4*)&sqw[m][jb];
            *(float4*)&sq[4] = *(const float4*)&sqw[m][jb + 4];
#pragma unroll
            for (int kk = 0; kk < 4; ++kk) {
                const float* pr = pmap + ((size_t)((kb + kk) * M_ + m)) * N_ + n0 + jb;
#pragma unroll
                for (int i = 0; i < 8; ++i) {
                    const bool valid = (n0 + jb + i) < N_;
                    const float p  = valid ? pr[i] : 0.f;
                    // elu(-p)+2: p<0 -> 2-p ; p>=0 -> exp(-p)+1
                    const float pe = (p < 0.f) ? (2.f - p) : (__expf(-p) + 1.f);
                    acc[i][kk] = fmaf(pe, sq[i] + ssk[kk] - 2.f * c[i][kk], acc[i][kk]);
                }
            }
        }
    }

    // ---- min over this thread's 8 n, then over the 16-lane n-group, then atomicMin ----
#pragma unroll
    for (int kk = 0; kk < 4; ++kk) {
        float lmin = __int_as_float(0x7F800000);  // +inf
#pragma unroll
        for (int i = 0; i < 8; ++i) {
            if (n0 + jb + i < N_) lmin = fminf(lmin, acc[i][kk]);
        }
        lmin = fminf(lmin, __shfl_xor(lmin, 1));
        lmin = fminf(lmin, __shfl_xor(lmin, 2));
        lmin = fminf(lmin, __shfl_xor(lmin, 4));
        lmin = fminf(lmin, __shfl_xor(lmin, 8));
        if (nig == 0) {
            atomicMin(out + (size_t)b * K_ + kb + kk, __float_as_uint(fmaxf(lmin, 0.f)));
        }
    }
}

extern "C" void kernel_launch(void* const* d_in, const int* in_sizes, int n_in,
                              void* d_out, int out_size, void* d_ws, size_t ws_size,
                              hipStream_t stream) {
    const float* x    = (const float*)d_in[0];   // (B, M, T)
    const float* shp  = (const float*)d_in[1];   // (K, L)
    const float* pmap = (const float*)d_in[2];   // (K, M, N)
    unsigned* out = (unsigned*)d_out;            // (B, K) float bits

    init_out_kernel<<<dim3((B_ * K_ + 255) / 256), dim3(256), 0, stream>>>(out);

    dim3 grid((N_ + TN - 1) / TN, B_);           // 16 x 64 = 1024 blocks
    shapelet_kernel<<<grid, dim3(NTHREADS), 0, stream>>>(x, shp, pmap, out);
}

// Round 4
// 205.957 us; speedup vs baseline: 1.0251x; 1.0251x over previous
//
#include <hip/hip_runtime.h>

// B=64, M=16, T=2048, L=64, K=32, N=1985
#define B_ 64
#define M_ 16
#define T_ 2048
#define L_ 64
#define K_ 32
#define N_ (T_ - L_ + 1)   // 1985
#define TN 128             // n-positions per block tile
#define NTH 256            // 16 n-groups (8n) x 16 k-groups (2k)
#define XSTR 212           // 192 data + cumulative skew (max col 211); 212%32=20
#define SHSTR 68           // sh2 row stride (64 + 4 pad) -> conflict-free b128 reads
#define SQSTR 132          // sqw row stride (128 + 4 pad)

// CUMULATIVE column skew: +4 floats per 32-float block (monotone -> injective;
// the round-2 alternating skew collided at cols 64..67 / 128..131 -> absmax 112).
// float4 groups are 4-aligned within a block, never straddle -> stay contiguous.
// Main-loop b128 reads: bank-group (2*nig+a+floor((2*nig+a)/8)) mod 8 -> 2-way (free).
__device__ __forceinline__ int xcol(int j) { return j + 4 * (j >> 5); }

__global__ void init_out_kernel(unsigned* __restrict__ out) {
    int i = blockIdx.x * 256 + threadIdx.x;
    if (i < B_ * K_) out[i] = 0x7F800000u;  // +inf
}

__global__ __launch_bounds__(NTH, 4)
void shapelet_kernel(const float* __restrict__ x,
                     const float* __restrict__ shp,
                     const float* __restrict__ pmap,
                     unsigned* __restrict__ out) {
    // LDS: 13568 + 8704 + 8448 + 128 = 30848 B -> 4 blocks/CU (123 KB of 160 KB)
    __shared__ __align__(16) float xs[M_][XSTR];    // x slice, skewed columns
    __shared__ __align__(16) float sh2[K_][SHSTR];  // shapelets [k][l], padded
    __shared__ __align__(16) float sqw[M_][SQSTR];  // sliding sum of x^2
    __shared__ __align__(16) float ss_l[K_];        // sum of s^2 per shapelet

    const int tid = threadIdx.x;
    const int b  = blockIdx.y;
    const int n0 = blockIdx.x * TN;

    // ---- stage x[b,:,n0..n0+191] as float4 groups (zero-fill past T) ----
    const float* xb = x + (size_t)b * (M_ * T_);
    for (int g = tid; g < M_ * 48; g += NTH) {
        int m  = g / 48;
        int j4 = (g - m * 48) * 4;
        int t  = n0 + j4;                       // 4-aligned; T_ is 4-aligned
        float4 v = make_float4(0.f, 0.f, 0.f, 0.f);
        if (t < T_) v = *(const float4*)(xb + m * T_ + t);
        *(float4*)&xs[m][xcol(j4)] = v;
    }
    // ---- stage shapelets sh2[k][l] (row-major copy, float4) ----
    for (int g = tid; g < K_ * 16; g += NTH) {
        int k  = g >> 4;
        int l4 = (g & 15) * 4;
        *(float4*)&sh2[k][l4] = *(const float4*)(shp + k * L_ + l4);
    }
    // ---- ss[k] = sum_l s[k,l]^2 ----
    if (tid < K_) {
        float s = 0.f;
        for (int l = 0; l < L_; ++l) { float v = shp[tid * L_ + l]; s = fmaf(v, v, s); }
        ss_l[tid] = s;
    }
    __syncthreads();

    // ---- sqw[m][j] = sum_{l<64} x^2 sliding window, 8 entries/thread ----
    {
        int m  = tid >> 4;
        int j0 = (tid & 15) * 8;
        float s = 0.f;
        for (int l = 0; l < L_; ++l) { float v = xs[m][xcol(j0 + l)]; s = fmaf(v, v, s); }
        sqw[m][j0] = s;
        for (int d = 1; d < 8; ++d) {
            float a = xs[m][xcol(j0 + d + L_ - 1)];
            float r = xs[m][xcol(j0 + d - 1)];
            s += a * a - r * r;
            sqw[m][j0 + d] = s;
        }
    }
    __syncthreads();

    // ---- per-thread micro-tile: 8 consecutive n x 2 k ----
    const int nig = tid & 15;
    const int kig = tid >> 4;        // 0..15
    const int jb  = nig * 8;
    const int kb  = kig * 2;

    const float ssk0 = ss_l[kb], ssk1 = ss_l[kb + 1];

    float acc[8][2];
#pragma unroll
    for (int i = 0; i < 8; ++i) { acc[i][0] = 0.f; acc[i][1] = 0.f; }

#pragma unroll 1
    for (int m2 = 0; m2 < M_; m2 += 2) {
        float c0[8][2], c1[8][2];
#pragma unroll
        for (int i = 0; i < 8; ++i) {
            c0[i][0] = 0.f; c0[i][1] = 0.f; c1[i][0] = 0.f; c1[i][1] = 0.f;
        }

        // rotating 16-float register windows over xs[m][jb + ...]
        float wv0[16], wv1[16];
        *(float4*)&wv0[0] = *(const float4*)&xs[m2    ][xcol(jb)];
        *(float4*)&wv0[4] = *(const float4*)&xs[m2    ][xcol(jb + 4)];
        *(float4*)&wv1[0] = *(const float4*)&xs[m2 + 1][xcol(jb)];
        *(float4*)&wv1[4] = *(const float4*)&xs[m2 + 1][xcol(jb + 4)];

#pragma unroll 1
        for (int cc = 0; cc < 4; ++cc) {         // rolled: keeps body ~5 KB (I$-safe)
#pragma unroll
            for (int p = 0; p < 4; ++p) {
                const int ch  = cc * 4 + p;
                const int dst = ((p + 2) * 4) & 15;  // slot of chunk ch+2 (cc-invariant)
                *(float4*)&wv0[dst] = *(const float4*)&xs[m2    ][xcol(jb + (ch + 2) * 4)];
                *(float4*)&wv1[dst] = *(const float4*)&xs[m2 + 1][xcol(jb + (ch + 2) * 4)];
                const float4 s0 = *(const float4*)&sh2[kb    ][ch * 4];  // 4 l's of k=kb
                const float4 s1 = *(const float4*)&sh2[kb + 1][ch * 4];
#pragma unroll
                for (int dl = 0; dl < 4; ++dl) {
                    const float sa = ((const float*)&s0)[dl];
                    const float sb = ((const float*)&s1)[dl];
#pragma unroll
                    for (int i = 0; i < 8; ++i) {
                        const int o = (p * 4 + dl + i) & 15;
                        const float xv0 = wv0[o];
                        const float xv1 = wv1[o];
                        c0[i][0] = fmaf(xv0, sa, c0[i][0]);
                        c0[i][1] = fmaf(xv0, sb, c0[i][1]);
                        c1[i][0] = fmaf(xv1, sa, c1[i][0]);
                        c1[i][1] = fmaf(xv1, sb, c1[i][1]);
                    }
                }
            }
        }

        // ---- apply penalty for the two m's ----
#pragma unroll
        for (int mm = 0; mm < 2; ++mm) {
            const int m = m2 + mm;
            float (&c)[8][2] = mm ? c1 : c0;
            float sq[8];
            *(float4*)&sq[0] = *(const float4*)&sqw[m][jb];
            *(float4*)&sq[4] = *(const float4*)&sqw[m][jb + 4];
#pragma unroll
            for (int kk = 0; kk < 2; ++kk) {
                const float* pr = pmap + ((size_t)((kb + kk) * M_ + m)) * N_ + n0 + jb;
                const float ssv = kk ? ssk1 : ssk0;
#pragma unroll
                for (int i = 0; i < 8; ++i) {
                    const bool valid = (n0 + jb + i) < N_;
                    const float p  = valid ? pr[i] : 0.f;
                    // elu(-p)+2: p<0 -> 2-p ; p>=0 -> exp(-p)+1
                    const float pe = (p < 0.f) ? (2.f - p) : (__expf(-p) + 1.f);
                    acc[i][kk] = fmaf(pe, fmaf(-2.f, c[i][kk], sq[i] + ssv), acc[i][kk]);
                }
            }
        }
    }

    // ---- min over 8 n, then over the 16-lane n-group, then one atomicMin ----
#pragma unroll
    for (int kk = 0; kk < 2; ++kk) {
        float lmin = __int_as_float(0x7F800000);
#pragma unroll
        for (int i = 0; i < 8; ++i) {
            if (n0 + jb + i < N_) lmin = fminf(lmin, acc[i][kk]);
        }
        lmin = fminf(lmin, __shfl_xor(lmin, 1));
        lmin = fminf(lmin, __shfl_xor(lmin, 2));
        lmin = fminf(lmin, __shfl_xor(lmin, 4));
        lmin = fminf(lmin, __shfl_xor(lmin, 8));
        if (nig == 0) {
            atomicMin(out + (size_t)b * K_ + kb + kk, __float_as_uint(fmaxf(lmin, 0.f)));
        }
    }
}

extern "C" void kernel_launch(void* const* d_in, const int* in_sizes, int n_in,
                              void* d_out, int out_size, void* d_ws, size_t ws_size,
                              hipStream_t stream) {
    const float* x    = (const float*)d_in[0];   // (B, M, T)
    const float* shp  = (const float*)d_in[1];   // (K, L)
    const float* pmap = (const float*)d_in[2];   // (K, M, N)
    unsigned* out = (unsigned*)d_out;            // (B, K) float bits

    init_out_kernel<<<dim3((B_ * K_ + 255) / 256), dim3(256), 0, stream>>>(out);

    dim3 grid((N_ + TN - 1) / TN, B_);           // 16 x 64 = 1024 blocks, 4/CU
    shapelet_kernel<<<grid, dim3(NTH), 0, stream>>>(x, shp, pmap, out);
}